// Round 5
// baseline (118.023 us; speedup 1.0000x reference)
//
#include <hip/hip_runtime.h>

#define KCODES 16384
#define CDIM   32
#define NROWS  8192
#define KSPLIT 8                  // chunks (blockIdx.y)
#define CHUNK  (KCODES/KSPLIT)    // 2048
#define WCODES (CHUNK/4)          // 512 codes per wave
#define NT     (WCODES/16)        // 32 MFMA code-tiles per wave
#define MARGIN 4.0f               // >>(f16 mfma err ~0.8 + tag noise ~0.2) in l-units

typedef _Float16 half8 __attribute__((ext_vector_type(8)));
typedef float    floatx4 __attribute__((ext_vector_type(4)));

// workspace layout (float indices)
#define WS_MSE   0
#define WS_PLP   1
#define WS_AVGP  16                      // [16384]
#define WS_ENORM (16 + KCODES)           // [16384] fp32, exact
#define WS_ZNORM (16 + 2*KCODES)         // [8192]  fp32
#define WS_PART  (16 + 2*KCODES + NROWS) // float4[KSPLIT][NROWS]
#define WS_E16   (WS_PART + 4*KSPLIT*NROWS)      // f16[16384][32]
#define WS_Z16   (WS_E16 + KCODES*16)            // f16[8192][32]

// output layout (floats): z_q [0, N*C), loss [N*C], idx [N*C+1, ...)
#define OUT_LOSS (NROWS*CDIM)
#define OUT_IDX  (NROWS*CDIM + 1)

// ---------------------------------------------------------------------------
// prep (R12-exact): blocks [0,64): e-rows (enorm + f16 + zero avg_probs);
// blocks [64,96): z-rows (znorm + f16); block 64 zeroes scalars.
// ---------------------------------------------------------------------------
__global__ __launch_bounds__(256) void prep_kernel(const float* __restrict__ z,
                                                   const float* __restrict__ emb,
                                                   float* __restrict__ ws) {
  const int tid = threadIdx.x;
  if (blockIdx.x < 64) {
    int k = blockIdx.x * 256 + tid;
    const float4* p = (const float4*)(emb + (size_t)k * CDIM);
    _Float16* e16 = (_Float16*)(ws + WS_E16);
    float s = 0.f;
    half8 h[4];
#pragma unroll
    for (int i = 0; i < 8; ++i) {
      float4 v = p[i];
      s += v.x*v.x + v.y*v.y + v.z*v.z + v.w*v.w;
      h[i>>1][(i&1)*4+0] = (_Float16)v.x;
      h[i>>1][(i&1)*4+1] = (_Float16)v.y;
      h[i>>1][(i&1)*4+2] = (_Float16)v.z;
      h[i>>1][(i&1)*4+3] = (_Float16)v.w;
    }
    ws[WS_ENORM + k] = s;
    ws[WS_AVGP + k]  = 0.f;
    half8* dst = (half8*)(e16 + (size_t)k*32);
#pragma unroll
    for (int i = 0; i < 4; ++i) dst[i] = h[i];
  } else {
    int b = blockIdx.x - 64;
    int n = b*256 + tid;
    if (b == 0 && tid < 16) ws[tid] = 0.f;
    _Float16* z16 = (_Float16*)(ws + WS_Z16);
    float s = 0.f;
    half8 h[4];
#pragma unroll
    for (int c = 0; c < CDIM; ++c) {
      float v = z[(size_t)b*8192 + c*256 + tid];
      s = fmaf(v, v, s);
      h[c>>3][c&7] = (_Float16)v;
    }
    ws[WS_ZNORM + n] = s;
    half8* dst = (half8*)(z16 + (size_t)n*32);
#pragma unroll
    for (int i = 0; i < 4; ++i) dst[i] = h[i];
  }
}

// ---------------------------------------------------------------------------
// gemm_pass v6: occupancy attack. Evidence chain:
//   R0: VGPR=28, AGPR shuttles, Occ 44-49%, 43.7us.
//   R2 (asm pins, lb(256,4)):   ~35us.
//   R3 (dist-2/3 pf, lb(256,5)): ~32.6us  (latency theory: -2.5 of -12 pred)
//   R4 (MFMA hoist, nonvol pins): ~32us   (MFMA-latency theory: dead)
//   => residual ~25us over ~7us issue floor is INSENSITIVE to intra-wave
//      scheduling. Only unexplored axis: inter-wave TLP. Occupancy never
//      re-measured since R0 (fills occlude top-5); lb caps it at 5/SIMD.
// Change: __launch_bounds__(256,8) -> 64-VGPR budget, 8 waves/SIMD; grid
//   (2048 blocks = 8 blocks/CU x 4 waves) fills all 32 slots/CU exactly.
//   Body slimmed to fit 64 regs: 2-phase role-swap (bc/bn named, no copies,
//   distance-1.5 prefetch), pins + asm screen kept (R2 win).
//   Live estimate: a0,a1(8) bc,bn(8) t1l,t2l(16) d(8) cb(4) ec,en(2)
//   ptrs(4) misc(6) ~= 56-60.
// Fallback if FETCH/WRITE balloon (spill): revert to lb(256,6).
// Tagged values bit-identical to R15 -> absmax must stay 0.0.
// ---------------------------------------------------------------------------
__global__ __launch_bounds__(256, 8) void gemm_pass(const float* __restrict__ ws_ro,
                                                    float* __restrict__ ws) {
  __shared__ float2 wdump[4][32];       // [wave][row] top-2 tagged floats

  const int tid  = threadIdx.x;
  const int wv   = tid >> 6;
  const int lane = tid & 63;
  const int nn   = lane & 15;
  const int quad = lane >> 4;
  const int n0   = blockIdx.x * 32;
  const int kb   = blockIdx.y * CHUNK + wv * WCODES;

  const half8* z16v = (const half8*)(ws_ro + WS_Z16);
  const half8* e16v = (const half8*)(ws_ro + WS_E16);
  const float* enorm = ws_ro + WS_ENORM;
  const float* znorm = ws_ro + WS_ZNORM;
  float4* part = (float4*)(ws + WS_PART);

  half8 a0 = z16v[(size_t)(n0 + nn)*4 + quad];
  half8 a1 = z16v[(size_t)(n0 + 16 + nn)*4 + quad];

  float t1l[8], t2l[8];
#pragma unroll
  for (int i = 0; i < 8; ++i) { t1l[i] = -3.0e38f; t2l[i] = -3.0e38f; }

  const int tagbase = wv*WCODES + nn;   // full within-chunk code of tile 0

  // tile-t bases: pb[t*64] (half8 units, 1024B/tile), pe[t*16] (64B/tile)
  const half8* pb = e16v + ((size_t)(kb + nn)*4 + quad);
  const float* pe = enorm + kb + nn;

  half8 bc = pb[0];  float ec = pe[0];  // tile t (phase A buffer)
  half8 bn;          float en;          // tile t+1 (phase B buffer)

  for (int t = 0; t < NT; t += 2) {
    // ---- phase A: prefetch t+1, compute tile t ----
    bn = pb[64];  en = pe[16];
    {
      float neh = -0.5f * ec;                   // broadcast bias: D = dot - en2/2
      floatx4 cb = {neh, neh, neh, neh};
      floatx4 d0 = __builtin_amdgcn_mfma_f32_16x16x32_f16(a0, bc, cb, 0, 0, 0);
      floatx4 d1 = __builtin_amdgcn_mfma_f32_16x16x32_f16(a1, bc, cb, 0, 0, 0);
      asm("" : "+v"(d0), "+v"(d1));             // non-volatile VGPR pin
      const int tg = tagbase + 16*t;            // 12-bit within-chunk code
#pragma unroll
      for (int i = 0; i < 8; ++i) {
        float lp = (i < 4) ? d0[i & 3] : d1[i & 3];
        float v  = __int_as_float((__float_as_int(lp) & 0xFFFFF000) | tg);
        asm("v_med3_f32 %0, %1, %2, %0" : "+v"(t2l[i]) : "v"(v), "v"(t1l[i]));
        asm("v_max_f32 %0, %1, %0"      : "+v"(t1l[i]) : "v"(v));
      }
    }
    // ---- phase B: prefetch t+2 (overwrites consumed bc), compute tile t+1 ----
    bc = pb[128];  ec = pe[32];                 // last iter: mapped overread, unused
    {
      float neh = -0.5f * en;
      floatx4 cb = {neh, neh, neh, neh};
      floatx4 d0 = __builtin_amdgcn_mfma_f32_16x16x32_f16(a0, bn, cb, 0, 0, 0);
      floatx4 d1 = __builtin_amdgcn_mfma_f32_16x16x32_f16(a1, bn, cb, 0, 0, 0);
      asm("" : "+v"(d0), "+v"(d1));
      const int tg = tagbase + 16*t + 16;
#pragma unroll
      for (int i = 0; i < 8; ++i) {
        float lp = (i < 4) ? d0[i & 3] : d1[i & 3];
        float v  = __int_as_float((__float_as_int(lp) & 0xFFFFF000) | tg);
        asm("v_med3_f32 %0, %1, %2, %0" : "+v"(t2l[i]) : "v"(v), "v"(t1l[i]));
        asm("v_max_f32 %0, %1, %0"      : "+v"(t1l[i]) : "v"(v));
      }
    }
    pb += 128; pe += 32;
  }

  // butterfly top-2 merge across the 16 nn-lanes (same-row exchanges only)
#pragma unroll
  for (int i = 0; i < 8; ++i) {
    float v1 = t1l[i], v2 = t2l[i];
#pragma unroll
    for (int m = 1; m < 16; m <<= 1) {
      float o1 = __shfl_xor(v1, m);
      float o2 = __shfl_xor(v2, m);
      float mn = fminf(v1, o1);
      v1 = fmaxf(v1, o1);
      v2 = fmaxf(mn, fmaxf(v2, o2));
    }
    if (nn == 0) wdump[wv][(i>>2)*16 + quad*4 + (i&3)] = make_float2(v1, v2);
  }
  __syncthreads();

  // merge 4 waves per row, unpack tags -> (l, code), apply -0.5*znorm here
  if (tid < 32) {
    float v1 = -3.0e38f, v2 = -3.0e38f;
#pragma unroll
    for (int w = 0; w < 4; ++w) {
      float2 p = wdump[w][tid];
      float mn = fminf(v1, p.x);
      v1 = fmaxf(v1, p.x);
      v2 = fmaxf(mn, fmaxf(v2, p.y));
    }
    float znh = 0.5f * znorm[n0 + tid];
    int b1 = __float_as_int(v1), b2 = __float_as_int(v2);
    int c1i = blockIdx.y*CHUNK + (b1 & 0xFFF);
    int c2i = blockIdx.y*CHUNK + (b2 & 0xFFF);
    float l1 = 200.f * (__int_as_float(b1 & 0xFFFFF000) - znh);
    float l2 = 200.f * (__int_as_float(b2 & 0xFFFFF000) - znh);
    part[(size_t)blockIdx.y*NROWS + n0 + tid] =
        make_float4(l1, __int_as_float(c1i), l2, __int_as_float(c2i));
  }
}

// ---------------------------------------------------------------------------
// combine (+fused zq) — R12-exact, NO gate/finalize tail. R15 showed the
// fused tail's 256 serialized agent-scope atomic loads cost ~50+ us; the
// dispatch-boundary finalize with plain loads is ~5 us (R1..R12 proven).
// ---------------------------------------------------------------------------
__global__ __launch_bounds__(64) void combine_kernel(const float* __restrict__ z,
                                                     const float* __restrict__ emb,
                                                     float* __restrict__ ws,
                                                     float* __restrict__ out) {
  const float4* part = (const float4*)(ws + WS_PART);
  int n = blockIdx.x*64 + threadIdx.x;

  float l[16]; int c[16];
#pragma unroll
  for (int ch = 0; ch < KSPLIT; ++ch) {
    float4 v = part[(size_t)ch*NROWS + n];
    l[ch*2+0] = v.x; c[ch*2+0] = __float_as_int(v.y);
    l[ch*2+1] = v.z; c[ch*2+1] = __float_as_int(v.w);
  }
  float mm = l[0];
#pragma unroll
  for (int i = 1; i < 16; ++i) mm = fmaxf(mm, l[i]);

  int bb = n >> 8, hw = n & 255;
  float zr[32];
  float zn = 0.f;
#pragma unroll
  for (int cc = 0; cc < CDIM; ++cc) {
    zr[cc] = z[(size_t)bb*8192 + cc*256 + hw];
    zn = fmaf(zr[cc], zr[cc], zn);
  }
  float bd = 3.0e38f; int bc = 0x7fffffff;
#pragma unroll
  for (int i = 0; i < 16; ++i) {
    if (l[i] > mm - MARGIN) {
      int code = c[i];
      const float4* er4 = (const float4*)(emb + (size_t)code*CDIM);
      float dot = 0.f;
#pragma unroll
      for (int q = 0; q < 8; ++q) {
        float4 e4 = er4[q];
        dot = fmaf(zr[q*4+0], e4.x, dot);
        dot = fmaf(zr[q*4+1], e4.y, dot);
        dot = fmaf(zr[q*4+2], e4.z, dot);
        dot = fmaf(zr[q*4+3], e4.w, dot);
      }
      float d = (zn + ws[WS_ENORM + code]) - 2.f*dot;   // exact fp32 distance
      if (d < bd || (d == bd && code < bc)) { bd = d; bc = code; }
    }
  }
  out[OUT_IDX + n] = (float)bc;

  // fused zq: straight-through output + MSE (coalesced per-c stores)
  const float* er = emb + (size_t)bc*CDIM;
  float msel = 0.f;
#pragma unroll
  for (int cc = 0; cc < CDIM; ++cc) {
    float zq = er[cc];
    float df = zq - zr[cc];
    msel = fmaf(df, df, msel);
    out[(size_t)bb*8192 + cc*256 + hw] = zr[cc] + (zq - zr[cc]);
  }
  for (int off = 1; off < 64; off <<= 1) msel += __shfl_xor(msel, off);
  if (threadIdx.x == 0) atomicAdd(&ws[WS_MSE], msel);

  // loss softmax from approx pairs (max term = exp(0)=1 -> NaN-proof)
  float s = 0.f;
#pragma unroll
  for (int i = 0; i < 16; ++i) s += __expf(l[i] - mm);
  float lse = mm + __logf(s);

  float plp = 0.f;
#pragma unroll
  for (int i = 0; i < 16; ++i) {
    float u = l[i] - lse;
    float p = __expf(u);
    plp = fmaf(p, u, plp);
    if (p > 1e-12f) atomicAdd(&ws[WS_AVGP + c[i]], p);
  }
  for (int off = 1; off < 64; off <<= 1) plp += __shfl_xor(plp, off);
  if (threadIdx.x == 0) atomicAdd(&ws[WS_PLP], plp);
}

// ---------------------------------------------------------------------------
// finalize (separate dispatch, plain loads — R12-exact): entropy + loss.
// ---------------------------------------------------------------------------
__global__ __launch_bounds__(256) void finalize_kernel(const float* __restrict__ ws,
                                                       float* __restrict__ out) {
  __shared__ float red[256];
  float h = 0.f;
  for (int k = threadIdx.x; k < KCODES; k += 256) {
    float ap = ws[WS_AVGP + k] * (1.f/8192.f);
    h += ap * __logf(ap + 1e-5f);
  }
  red[threadIdx.x] = h;
  __syncthreads();
  for (int st = 128; st > 0; st >>= 1) {
    if (threadIdx.x < st) red[threadIdx.x] += red[threadIdx.x + st];
    __syncthreads();
  }
  if (threadIdx.x == 0) {
    float mse        = ws[WS_MSE] * (1.f/(8192.f*32.f));
    float sample_ent = -ws[WS_PLP] * (1.f/8192.f);
    out[OUT_LOSS] = 1.25f*mse + 0.1f*(sample_ent + red[0]);
  }
}

extern "C" void kernel_launch(void* const* d_in, const int* in_sizes, int n_in,
                              void* d_out, int out_size, void* d_ws, size_t ws_size,
                              hipStream_t stream) {
  (void)in_sizes; (void)n_in; (void)out_size; (void)ws_size;
  const float* z   = (const float*)d_in[0];
  const float* emb = (const float*)d_in[1];
  float* out = (float*)d_out;
  float* ws  = (float*)d_ws;

  prep_kernel    <<<96, 256, 0, stream>>>(z, emb, ws);
  gemm_pass      <<<dim3(NROWS/32, KSPLIT), 256, 0, stream>>>(ws, ws);
  combine_kernel <<<NROWS/64, 64, 0, stream>>>(z, emb, ws, out);
  finalize_kernel<<<1, 256, 0, stream>>>(ws, out);
}

// Round 7
// 116.561 us; speedup vs baseline: 1.0125x; 1.0125x over previous
//
#include <hip/hip_runtime.h>

#define KCODES 16384
#define CDIM   32
#define NROWS  8192
#define KSPLIT 8                  // chunks (blockIdx.y)
#define CHUNK  (KCODES/KSPLIT)    // 2048
#define WCODES (CHUNK/4)          // 512 codes per wave
#define NT     (WCODES/16)        // 32 MFMA code-tiles per wave
#define RPB    64                 // rows per block (R6: was 32; halves e16 L2 traffic)
#define MARGIN 4.0f               // >>(f16 mfma err ~0.8 + tag noise ~0.2) in l-units

typedef _Float16 half8 __attribute__((ext_vector_type(8)));
typedef float    floatx4 __attribute__((ext_vector_type(4)));

// workspace layout (float indices)
#define WS_MSE   0
#define WS_PLP   1
#define WS_AVGP  16                      // [16384]
#define WS_ENORM (16 + KCODES)           // [16384] fp32, exact
#define WS_ZNORM (16 + 2*KCODES)         // [8192]  fp32
#define WS_PART  (16 + 2*KCODES + NROWS) // float4[KSPLIT][NROWS]
#define WS_E16   (WS_PART + 4*KSPLIT*NROWS)      // f16[16384][32]
#define WS_Z16   (WS_E16 + KCODES*16)            // f16[8192][32]

// output layout (floats): z_q [0, N*C), loss [N*C], idx [N*C+1, ...)
#define OUT_LOSS (NROWS*CDIM)
#define OUT_IDX  (NROWS*CDIM + 1)

// ---------------------------------------------------------------------------
// prep (R12-exact): blocks [0,64): e-rows (enorm + f16 + zero avg_probs);
// blocks [64,96): z-rows (znorm + f16); block 64 zeroes scalars.
// ---------------------------------------------------------------------------
__global__ __launch_bounds__(256) void prep_kernel(const float* __restrict__ z,
                                                   const float* __restrict__ emb,
                                                   float* __restrict__ ws) {
  const int tid = threadIdx.x;
  if (blockIdx.x < 64) {
    int k = blockIdx.x * 256 + tid;
    const float4* p = (const float4*)(emb + (size_t)k * CDIM);
    _Float16* e16 = (_Float16*)(ws + WS_E16);
    float s = 0.f;
    half8 h[4];
#pragma unroll
    for (int i = 0; i < 8; ++i) {
      float4 v = p[i];
      s += v.x*v.x + v.y*v.y + v.z*v.z + v.w*v.w;
      h[i>>1][(i&1)*4+0] = (_Float16)v.x;
      h[i>>1][(i&1)*4+1] = (_Float16)v.y;
      h[i>>1][(i&1)*4+2] = (_Float16)v.z;
      h[i>>1][(i&1)*4+3] = (_Float16)v.w;
    }
    ws[WS_ENORM + k] = s;
    ws[WS_AVGP + k]  = 0.f;
    half8* dst = (half8*)(e16 + (size_t)k*32);
#pragma unroll
    for (int i = 0; i < 4; ++i) dst[i] = h[i];
  } else {
    int b = blockIdx.x - 64;
    int n = b*256 + tid;
    if (b == 0 && tid < 16) ws[tid] = 0.f;
    _Float16* z16 = (_Float16*)(ws + WS_Z16);
    float s = 0.f;
    half8 h[4];
#pragma unroll
    for (int c = 0; c < CDIM; ++c) {
      float v = z[(size_t)b*8192 + c*256 + tid];
      s = fmaf(v, v, s);
      h[c>>3][c&7] = (_Float16)v;
    }
    ws[WS_ZNORM + n] = s;
    half8* dst = (half8*)(z16 + (size_t)n*32);
#pragma unroll
    for (int i = 0; i < 4; ++i) dst[i] = h[i];
  }
}

// ---------------------------------------------------------------------------
// gemm_pass v7 (resubmit; R6 was an infra failure, kernel audited clean).
// Memory-path-traffic attack. Evidence chain:
//   R0: AGPR shuttles, 43.7us -> R2 pins: ~35 -> R3 deep prefetch: ~32.6
//   R4 MFMA hoist: ~32 -> R5 occupancy 8/SIMD: ~32. Latency AND occupancy
//   insensitive => throughput cap, not latency. Unmodeled cap: each block
//   streams its 128KB e16 chunk through L1/L2; 2048 blocks x 128KB = 256MB
//   at ~8 TB/s sustained = 32us. VALU floor ~6us, L2-spec floor ~7.4us.
// Change: RPB 32 -> 64 (halves row-blocks => 128MB e16 traffic). Grid
//   (128,8) = 4 blocks/CU x 4 waves = 16 waves/CU at lb(256,4) (128 regs;
//   live ~98: a0..a3=16, t1l/t2l=32, bc/bn=16, d0..d3=16, cb=4, misc~14).
//   Per-(row,chunk) candidate stream/tags/order unchanged -> part[] bit-
//   identical -> absmax 0.0.
// A/B readout: memory-bound -> gemm ~17-20us (total ~104); VALU-bound ->
//   flat (next: serialization diagnostic for top-5 visibility); spill ->
//   FETCH/WRITE balloon (revert to RPB=32).
// ---------------------------------------------------------------------------
__global__ __launch_bounds__(256, 4) void gemm_pass(const float* __restrict__ ws_ro,
                                                    float* __restrict__ ws) {
  __shared__ float2 wdump[4][RPB];      // [wave][row] top-2 tagged floats

  const int tid  = threadIdx.x;
  const int wv   = tid >> 6;
  const int lane = tid & 63;
  const int nn   = lane & 15;
  const int quad = lane >> 4;
  const int n0   = blockIdx.x * RPB;
  const int kb   = blockIdx.y * CHUNK + wv * WCODES;

  const half8* z16v = (const half8*)(ws_ro + WS_Z16);
  const half8* e16v = (const half8*)(ws_ro + WS_E16);
  const float* enorm = ws_ro + WS_ENORM;
  const float* znorm = ws_ro + WS_ZNORM;
  float4* part = (float4*)(ws + WS_PART);

  half8 a0 = z16v[(size_t)(n0 + nn)*4 + quad];
  half8 a1 = z16v[(size_t)(n0 + 16 + nn)*4 + quad];
  half8 a2 = z16v[(size_t)(n0 + 32 + nn)*4 + quad];
  half8 a3 = z16v[(size_t)(n0 + 48 + nn)*4 + quad];

  float t1l[16], t2l[16];
#pragma unroll
  for (int i = 0; i < 16; ++i) { t1l[i] = -3.0e38f; t2l[i] = -3.0e38f; }

  const int tagbase = wv*WCODES + nn;   // full within-chunk code of tile 0

  // tile-t bases: pb[t*64] (half8 units, 1024B/tile), pe[t*16] (64B/tile)
  const half8* pb = e16v + ((size_t)(kb + nn)*4 + quad);
  const float* pe = enorm + kb + nn;

  half8 bc = pb[0];  float ec = pe[0];  // tile t (phase A buffer)
  half8 bn;          float en;          // tile t+1 (phase B buffer)

  for (int t = 0; t < NT; t += 2) {
    // ---- phase A: prefetch t+1, compute tile t over 4 row-groups ----
    bn = pb[64];  en = pe[16];
    {
      float neh = -0.5f * ec;                   // broadcast bias: D = dot - en2/2
      floatx4 cb = {neh, neh, neh, neh};
      floatx4 d0 = __builtin_amdgcn_mfma_f32_16x16x32_f16(a0, bc, cb, 0, 0, 0);
      floatx4 d1 = __builtin_amdgcn_mfma_f32_16x16x32_f16(a1, bc, cb, 0, 0, 0);
      floatx4 d2 = __builtin_amdgcn_mfma_f32_16x16x32_f16(a2, bc, cb, 0, 0, 0);
      floatx4 d3 = __builtin_amdgcn_mfma_f32_16x16x32_f16(a3, bc, cb, 0, 0, 0);
      asm("" : "+v"(d0), "+v"(d1), "+v"(d2), "+v"(d3));   // non-volatile VGPR pin
      const int tg = tagbase + 16*t;            // 12-bit within-chunk code
#pragma unroll
      for (int i = 0; i < 16; ++i) {
        float lp = (i < 4) ? d0[i & 3] : (i < 8) ? d1[i & 3]
                 : (i < 12) ? d2[i & 3] : d3[i & 3];
        float v  = __int_as_float((__float_as_int(lp) & 0xFFFFF000) | tg);
        asm("v_med3_f32 %0, %1, %2, %0" : "+v"(t2l[i]) : "v"(v), "v"(t1l[i]));
        asm("v_max_f32 %0, %1, %0"      : "+v"(t1l[i]) : "v"(v));
      }
    }
    // ---- phase B: prefetch t+2 (overwrites consumed bc), compute tile t+1 ----
    bc = pb[128];  ec = pe[32];                 // last iter: mapped overread, unused
    {
      float neh = -0.5f * en;
      floatx4 cb = {neh, neh, neh, neh};
      floatx4 d0 = __builtin_amdgcn_mfma_f32_16x16x32_f16(a0, bn, cb, 0, 0, 0);
      floatx4 d1 = __builtin_amdgcn_mfma_f32_16x16x32_f16(a1, bn, cb, 0, 0, 0);
      floatx4 d2 = __builtin_amdgcn_mfma_f32_16x16x32_f16(a2, bn, cb, 0, 0, 0);
      floatx4 d3 = __builtin_amdgcn_mfma_f32_16x16x32_f16(a3, bn, cb, 0, 0, 0);
      asm("" : "+v"(d0), "+v"(d1), "+v"(d2), "+v"(d3));
      const int tg = tagbase + 16*t + 16;
#pragma unroll
      for (int i = 0; i < 16; ++i) {
        float lp = (i < 4) ? d0[i & 3] : (i < 8) ? d1[i & 3]
                 : (i < 12) ? d2[i & 3] : d3[i & 3];
        float v  = __int_as_float((__float_as_int(lp) & 0xFFFFF000) | tg);
        asm("v_med3_f32 %0, %1, %2, %0" : "+v"(t2l[i]) : "v"(v), "v"(t1l[i]));
        asm("v_max_f32 %0, %1, %0"      : "+v"(t1l[i]) : "v"(v));
      }
    }
    pb += 128; pe += 32;
  }

  // butterfly top-2 merge across the 16 nn-lanes (same-row exchanges only)
  // row of (i, quad): (i>>2)*16 + quad*4 + (i&3)  in [0, RPB)
#pragma unroll
  for (int i = 0; i < 16; ++i) {
    float v1 = t1l[i], v2 = t2l[i];
#pragma unroll
    for (int m = 1; m < 16; m <<= 1) {
      float o1 = __shfl_xor(v1, m);
      float o2 = __shfl_xor(v2, m);
      float mn = fminf(v1, o1);
      v1 = fmaxf(v1, o1);
      v2 = fmaxf(mn, fmaxf(v2, o2));
    }
    if (nn == 0) wdump[wv][(i>>2)*16 + quad*4 + (i&3)] = make_float2(v1, v2);
  }
  __syncthreads();

  // merge 4 waves per row, unpack tags -> (l, code), apply -0.5*znorm here
  if (tid < RPB) {
    float v1 = -3.0e38f, v2 = -3.0e38f;
#pragma unroll
    for (int w = 0; w < 4; ++w) {
      float2 p = wdump[w][tid];
      float mn = fminf(v1, p.x);
      v1 = fmaxf(v1, p.x);
      v2 = fmaxf(mn, fmaxf(v2, p.y));
    }
    float znh = 0.5f * znorm[n0 + tid];
    int b1 = __float_as_int(v1), b2 = __float_as_int(v2);
    int c1i = blockIdx.y*CHUNK + (b1 & 0xFFF);
    int c2i = blockIdx.y*CHUNK + (b2 & 0xFFF);
    float l1 = 200.f * (__int_as_float(b1 & 0xFFFFF000) - znh);
    float l2 = 200.f * (__int_as_float(b2 & 0xFFFFF000) - znh);
    part[(size_t)blockIdx.y*NROWS + n0 + tid] =
        make_float4(l1, __int_as_float(c1i), l2, __int_as_float(c2i));
  }
}

// ---------------------------------------------------------------------------
// combine (+fused zq) — R12-exact, NO gate/finalize tail. R15 showed the
// fused tail's 256 serialized agent-scope atomic loads cost ~50+ us; the
// dispatch-boundary finalize with plain loads is ~5 us (R1..R12 proven).
// ---------------------------------------------------------------------------
__global__ __launch_bounds__(64) void combine_kernel(const float* __restrict__ z,
                                                     const float* __restrict__ emb,
                                                     float* __restrict__ ws,
                                                     float* __restrict__ out) {
  const float4* part = (const float4*)(ws + WS_PART);
  int n = blockIdx.x*64 + threadIdx.x;

  float l[16]; int c[16];
#pragma unroll
  for (int ch = 0; ch < KSPLIT; ++ch) {
    float4 v = part[(size_t)ch*NROWS + n];
    l[ch*2+0] = v.x; c[ch*2+0] = __float_as_int(v.y);
    l[ch*2+1] = v.z; c[ch*2+1] = __float_as_int(v.w);
  }
  float mm = l[0];
#pragma unroll
  for (int i = 1; i < 16; ++i) mm = fmaxf(mm, l[i]);

  int bb = n >> 8, hw = n & 255;
  float zr[32];
  float zn = 0.f;
#pragma unroll
  for (int cc = 0; cc < CDIM; ++cc) {
    zr[cc] = z[(size_t)bb*8192 + cc*256 + hw];
    zn = fmaf(zr[cc], zr[cc], zn);
  }
  float bd = 3.0e38f; int bc = 0x7fffffff;
#pragma unroll
  for (int i = 0; i < 16; ++i) {
    if (l[i] > mm - MARGIN) {
      int code = c[i];
      const float4* er4 = (const float4*)(emb + (size_t)code*CDIM);
      float dot = 0.f;
#pragma unroll
      for (int q = 0; q < 8; ++q) {
        float4 e4 = er4[q];
        dot = fmaf(zr[q*4+0], e4.x, dot);
        dot = fmaf(zr[q*4+1], e4.y, dot);
        dot = fmaf(zr[q*4+2], e4.z, dot);
        dot = fmaf(zr[q*4+3], e4.w, dot);
      }
      float d = (zn + ws[WS_ENORM + code]) - 2.f*dot;   // exact fp32 distance
      if (d < bd || (d == bd && code < bc)) { bd = d; bc = code; }
    }
  }
  out[OUT_IDX + n] = (float)bc;

  // fused zq: straight-through output + MSE (coalesced per-c stores)
  const float* er = emb + (size_t)bc*CDIM;
  float msel = 0.f;
#pragma unroll
  for (int cc = 0; cc < CDIM; ++cc) {
    float zq = er[cc];
    float df = zq - zr[cc];
    msel = fmaf(df, df, msel);
    out[(size_t)bb*8192 + cc*256 + hw] = zr[cc] + (zq - zr[cc]);
  }
  for (int off = 1; off < 64; off <<= 1) msel += __shfl_xor(msel, off);
  if (threadIdx.x == 0) atomicAdd(&ws[WS_MSE], msel);

  // loss softmax from approx pairs (max term = exp(0)=1 -> NaN-proof)
  float s = 0.f;
#pragma unroll
  for (int i = 0; i < 16; ++i) s += __expf(l[i] - mm);
  float lse = mm + __logf(s);

  float plp = 0.f;
#pragma unroll
  for (int i = 0; i < 16; ++i) {
    float u = l[i] - lse;
    float p = __expf(u);
    plp = fmaf(p, u, plp);
    if (p > 1e-12f) atomicAdd(&ws[WS_AVGP + c[i]], p);
  }
  for (int off = 1; off < 64; off <<= 1) plp += __shfl_xor(plp, off);
  if (threadIdx.x == 0) atomicAdd(&ws[WS_PLP], plp);
}

// ---------------------------------------------------------------------------
// finalize (separate dispatch, plain loads — R12-exact): entropy + loss.
// ---------------------------------------------------------------------------
__global__ __launch_bounds__(256) void finalize_kernel(const float* __restrict__ ws,
                                                       float* __restrict__ out) {
  __shared__ float red[256];
  float h = 0.f;
  for (int k = threadIdx.x; k < KCODES; k += 256) {
    float ap = ws[WS_AVGP + k] * (1.f/8192.f);
    h += ap * __logf(ap + 1e-5f);
  }
  red[threadIdx.x] = h;
  __syncthreads();
  for (int st = 128; st > 0; st >>= 1) {
    if (threadIdx.x < st) red[threadIdx.x] += red[threadIdx.x + st];
    __syncthreads();
  }
  if (threadIdx.x == 0) {
    float mse        = ws[WS_MSE] * (1.f/(8192.f*32.f));
    float sample_ent = -ws[WS_PLP] * (1.f/8192.f);
    out[OUT_LOSS] = 1.25f*mse + 0.1f*(sample_ent + red[0]);
  }
}

extern "C" void kernel_launch(void* const* d_in, const int* in_sizes, int n_in,
                              void* d_out, int out_size, void* d_ws, size_t ws_size,
                              hipStream_t stream) {
  (void)in_sizes; (void)n_in; (void)out_size; (void)ws_size;
  const float* z   = (const float*)d_in[0];
  const float* emb = (const float*)d_in[1];
  float* out = (float*)d_out;
  float* ws  = (float*)d_ws;

  prep_kernel    <<<96, 256, 0, stream>>>(z, emb, ws);
  gemm_pass      <<<dim3(NROWS/RPB, KSPLIT), 256, 0, stream>>>(ws, ws);
  combine_kernel <<<NROWS/64, 64, 0, stream>>>(z, emb, ws, out);
  finalize_kernel<<<1, 256, 0, stream>>>(ws, out);
}